// Round 5
// baseline (283.905 us; speedup 1.0000x reference)
//
#include <hip/hip_runtime.h>
#include <math.h>

#define B 128
#define M 32
#define P 8732
#define C 21
#define ALPHA 10.0f
#define TPB2 256
#define PPB 256          // priors per block in fused kernel (1 per lane, 64 per wave)
#define NB2 35           // ceil(P / PPB)
#define CH 8             // k1 prior chunks
#define CS 1092          // ceil(P / CH)
#define NR4 9            // ceil((P/4) / TPB2) float4-groups per thread in phase B

// direct global->LDS DMA, 16 B/lane, wave-uniform LDS base + lane*16 scatter
#define GLD16(g, l)                                                   \
  __builtin_amdgcn_global_load_lds(                                   \
      (__attribute__((address_space(1))) void*)(g),                   \
      (__attribute__((address_space(3))) void*)(l), 16, 0, 0)

// agent-scope relaxed store: sc1 write-through — reaches the MALL (cross-XCD
// coherence point) without any buffer_wbl2 L2 flush.
#define ST_AGENT(p, v) \
  __hip_atomic_store((p), (v), __ATOMIC_RELAXED, __HIP_MEMORY_SCOPE_AGENT)
// agent-scope relaxed load: sc1 MALL-direct read. Per-load bypass instead of
// the full-L2 buffer_inv acquire fence (which thrashed co-resident blocks'
// L2 in R3/R4 — the 3x phase-A slowdown).
#define LD_AGENT_F(p) \
  __hip_atomic_load((p), __ATOMIC_RELAXED, __HIP_MEMORY_SCOPE_AGENT)
#define LD_AGENT_I(p) \
  __hip_atomic_load((p), __ATOMIC_RELAXED, __HIP_MEMORY_SCOPE_AGENT)

// ---------------- k1a: per-chunk best prior per object (partials) -----------
__global__ __launch_bounds__(256) void k1_partial(
    const float* __restrict__ b_boxes, const float* __restrict__ priors,
    float* __restrict__ pI, float* __restrict__ pU, int* __restrict__ pidx,
    int* __restrict__ done, int* __restrict__ imgcnt) {
  if (blockIdx.x == 0) {
    if (threadIdx.x == 0) *done = 0;
    if (threadIdx.x < B) imgcnt[threadIdx.x] = 0;  // per-image block counters
  }
  int b = blockIdx.x >> 3;
  int ch = blockIdx.x & 7;
  int wid = threadIdx.x >> 6;
  int lane = threadIdx.x & 63;
  int obase = wid * 8;

  float ox1[8], oy1[8], ox2[8], oy2[8], oarea[8], bI[8], bU[8];
  int bidx[8];
#pragma unroll
  for (int k = 0; k < 8; k++) {
    float4 bx = ((const float4*)b_boxes)[(size_t)b * M + obase + k];
    ox1[k] = bx.x; oy1[k] = bx.y; ox2[k] = bx.z; oy2[k] = bx.w;
    oarea[k] = (bx.z - bx.x) * (bx.w - bx.y);
    bI[k] = -1.0f; bU[k] = 1.0f; bidx[k] = P;
  }

  int pend = (ch + 1) * CS;
  if (pend > P) pend = P;
#pragma unroll 2
  for (int p = ch * CS + lane; p < pend; p += 64) {
    float4 pr = ((const float4*)priors)[p];
    float pw2 = pr.z * 0.5f, ph2 = pr.w * 0.5f;
    float px1 = pr.x - pw2, py1 = pr.y - ph2;
    float px2 = pr.x + pw2, py2 = pr.y + ph2;
    float areaP = pr.z * pr.w;
#pragma unroll
    for (int k = 0; k < 8; k++) {
      float iw = fminf(ox2[k], px2) - fmaxf(ox1[k], px1);
      float ih = fminf(oy2[k], py2) - fmaxf(oy1[k], py1);
      iw = fmaxf(iw, 0.0f);
      ih = fmaxf(ih, 0.0f);
      float inter = iw * ih;
      float uni = oarea[k] + areaP - inter;
      if (inter * bU[k] > bI[k] * uni) { bI[k] = inter; bU[k] = uni; bidx[k] = p; }
    }
  }
  for (int off = 32; off >= 1; off >>= 1) {
#pragma unroll
    for (int k = 0; k < 8; k++) {
      float oI = __shfl_xor(bI[k], off, 64);
      float oU = __shfl_xor(bU[k], off, 64);
      int oi = __shfl_xor(bidx[k], off, 64);
      float l = oI * bU[k], r = bI[k] * oU;
      if (l > r || (l == r && oi < bidx[k])) { bI[k] = oI; bU[k] = oU; bidx[k] = oi; }
    }
  }
  if (lane == 0) {
#pragma unroll
    for (int k = 0; k < 8; k++) {
      int idx = ((size_t)b * M + obase + k) * CH + ch;
      pI[idx] = bI[k]; pU[idx] = bU[k]; pidx[idx] = bidx[k];
    }
  }
}

// ---------------- fused k2+k3: per-prior match + CE, then per-image ---------
// hard-negative top-K done by the LAST block of each image (done-counter
// pattern). Cross-XCD handoff: sc1 write-through stores + vmcnt drain +
// relaxed agent atomics on the writer; sc1 MALL-direct loads on the reader.
// NO fences anywhere: no wbl2 (R1's 325us regression), no buffer_inv
// (R3/R4's L2-thrash 3x slowdown).
__global__ __launch_bounds__(TPB2) void k23_fused(
    const float* __restrict__ pred_loc, const float* __restrict__ pred_cls,
    const float* __restrict__ b_boxes, const int* __restrict__ b_labels,
    const float* __restrict__ priors,
    const float* __restrict__ pI, const float* __restrict__ pU,
    const int* __restrict__ pidx,
    float* __restrict__ ploc, float* __restrict__ pce, int* __restrict__ pnp,
    float* __restrict__ confneg, int* __restrict__ imgcnt,
    float* __restrict__ imgres, int* __restrict__ done,
    float* __restrict__ out) {
  int b = blockIdx.y;
  int p0 = blockIdx.x * PPB;
  int tid = threadIdx.x;
  int wid = tid >> 6;
  int lane = tid & 63;

  __shared__ __align__(16) union SU {
    struct {
      float cls[4][64 * C];  // 21504 B (wave-private class tiles)
      float4 box[M];
      float area[M];
      int lab[M];
      int obj[M];
      int inv[PPB];
    } a;
    struct {               // phase B (select) scratch — reuses phase-A LDS
      int histw[4 * 256];  // per-wave radix histograms
      int cnt[256];
      float rsum[4];
      int rcnt[4];
      float rl[4], rc[4], rh[4], rn[4];
    } s3;
  } u;
  __shared__ float rloc[4], rce[4];
  __shared__ int rnp[4];
  __shared__ int sdig, scum, sLastBlk, sLastImg, sK;
  __shared__ float sLoc, sCe, sNp;

  // ---------------- phase A: identical structure to the 214us k2 ------------
  {
    int wp0 = p0 + wid * 64;
    int nv = P - wp0;
    nv = nv < 0 ? 0 : (nv > 64 ? 64 : nv);
    int nf4 = (nv * C) >> 2;  // 336 (full), 147 (tail), or 0
    const float4* src = (const float4*)(pred_cls + ((size_t)b * P + wp0) * C);
#pragma unroll
    for (int k = 0; k < 6; k++) {
      int idx = (k << 6) + lane;
      if (idx < nf4) GLD16(src + idx, &u.a.cls[wid][k << 8]);
    }
  }

  u.a.inv[tid] = 0x7fffffff;
  if (tid < M) {
    int m = tid;
    float4 bx = ((const float4*)b_boxes)[b * M + m];
    u.a.box[m] = bx;
    u.a.area[m] = (bx.z - bx.x) * (bx.w - bx.y);
    u.a.lab[m] = b_labels[b * M + m];
    // fused k1_reduce: fold 8 chunk partials for object m of image b
    int o = b * M + m;
    float cI = pI[o * CH], cU = pU[o * CH];
    int ci = pidx[o * CH];
#pragma unroll
    for (int ch = 1; ch < CH; ch++) {
      float nI = pI[o * CH + ch], nU = pU[o * CH + ch];
      int ni = pidx[o * CH + ch];
      if (nI * cU > cI * nU) { cI = nI; cU = nU; ci = ni; }
    }
    u.a.obj[m] = ci;
  }
  __syncthreads();
  if (tid < M) {
    int t = u.a.obj[tid] - p0;
    if (t >= 0 && t < PPB) atomicMin(&u.a.inv[t], tid);
  }
  __syncthreads();  // drains the global_load_lds vmcnt + orders inv

  float locpart = 0.0f, cepospart = 0.0f;
  int npos = 0;
  int p = p0 + tid;
  if (p < P) {
    float4 pr = ((const float4*)priors)[p];
    float pw2 = pr.z * 0.5f, ph2 = pr.w * 0.5f;
    float px1 = pr.x - pw2, py1 = pr.y - ph2;
    float px2 = pr.x + pw2, py2 = pr.y + ph2;
    float areaP = pr.z * pr.w;
    float bI = -1.0f, bU = 1.0f;
    int bm = 0;
    for (int m = 0; m < M; m++) {
      float4 bx = u.a.box[m];  // one ds_read_b128 broadcast per object
      float iw = fminf(bx.z, px2) - fmaxf(bx.x, px1);
      float ih = fminf(bx.w, py2) - fmaxf(bx.y, py1);
      iw = fmaxf(iw, 0.0f);
      ih = fmaxf(ih, 0.0f);
      float inter = iw * ih;
      float uni = u.a.area[m] + areaP - inter;
      if (inter * bU > bI * uni) { bI = inter; bU = uni; bm = m; }
    }
    // forced best-prior override (first-max semantics preserved)
    int fm = u.a.inv[tid];
    if (fm != 0x7fffffff) {
      if (!((bI == bU) && (bm < fm))) { bI = 1.0f; bU = 1.0f; bm = fm; }
    }
    bool pos = (2.0f * bI >= bU);  // iou >= 0.5, division-free
    int wAny = __any((int)pos);

    if (wAny) {  // wave-uniform positive path: loc load + encode + L1 loss
      float4 pl = ((const float4*)pred_loc)[(size_t)b * P + p];
      float4 bx = u.a.box[bm];
      float cx = (bx.x + bx.z) * 0.5f, cy = (bx.y + bx.w) * 0.5f;
      float w = bx.z - bx.x, h = bx.w - bx.y;
      float rz = __builtin_amdgcn_rcpf(pr.z);
      float rw = __builtin_amdgcn_rcpf(pr.w);
      float g0 = (cx - pr.x) * 10.0f * rz;
      float g1 = (cy - pr.y) * 10.0f * rw;
      float g2 = __logf(w * rz) * 5.0f;
      float g3 = __logf(h * rw) * 5.0f;
      if (pos) {
        locpart = fabsf(pl.x - g0) + fabsf(pl.y - g1) +
                  fabsf(pl.z - g2) + fabsf(pl.w - g3);
        npos = 1;
      }
    }

    // CE from LDS (unstabilized logsumexp; verified absmax 0.0 since R9)
    const float* cptr = &u.a.cls[wid][lane * C];
    int cls = pos ? u.a.lab[bm] : 0;
    float se = 0.0f, vc = 0.0f;
#pragma unroll
    for (int c = 0; c < C; c++) {
      float x = cptr[c];
      se += __expf(x);
      if (c == cls) vc = x;  // predicated select, constant index
    }
    float ce = __logf(se) - vc;
    ST_AGENT(&confneg[(size_t)b * P + p], pos ? 0.0f : ce);  // sc1: reaches L3
    cepospart = pos ? ce : 0.0f;
  }

  for (int off = 32; off >= 1; off >>= 1) {
    locpart += __shfl_down(locpart, off, 64);
    cepospart += __shfl_down(cepospart, off, 64);
    npos += __shfl_down(npos, off, 64);
  }
  if (lane == 0) { rloc[wid] = locpart; rce[wid] = cepospart; rnp[wid] = npos; }
  // every wave drains its own sc1 confneg stores to the coherence point
  asm volatile("s_waitcnt vmcnt(0)" ::: "memory");
  __syncthreads();
  if (tid == 0) {
    int f = b * NB2 + blockIdx.x;
    ST_AGENT(&ploc[f], rloc[0] + rloc[1] + rloc[2] + rloc[3]);
    ST_AGENT(&pce[f], rce[0] + rce[1] + rce[2] + rce[3]);
    ST_AGENT(&pnp[f], rnp[0] + rnp[1] + rnp[2] + rnp[3]);
    asm volatile("s_waitcnt vmcnt(0)" ::: "memory");  // partials at L3
    int prev = __hip_atomic_fetch_add(&imgcnt[b], 1, __ATOMIC_RELAXED,
                                      __HIP_MEMORY_SCOPE_AGENT);
    sLastBlk = (prev == NB2 - 1) ? 1 : 0;
  }
  __syncthreads();
  if (!sLastBlk) return;
  // NO acquire fence here: reads below are sc1 MALL-direct, so no L2
  // invalidation is needed (and none happens — co-resident phase-A blocks
  // keep their L2 working set).

  // ---------------- phase B: this image's hard-negative top-K ---------------
  if (wid == 0) {  // reduce this image's 35 per-block partials (MALL-direct)
    float lp = 0.0f, cp = 0.0f;
    int np = 0;
    if (lane < NB2) {
      int f = b * NB2 + lane;
      lp = LD_AGENT_F(&ploc[f]);
      cp = LD_AGENT_F(&pce[f]);
      np = LD_AGENT_I(&pnp[f]);
    }
    for (int off = 32; off >= 1; off >>= 1) {
      lp += __shfl_down(lp, off, 64);
      cp += __shfl_down(cp, off, 64);
      np += __shfl_down(np, off, 64);
    }
    if (lane == 0) {
      int K = np * 3;
      if (K > P) K = P;
      sK = K; sLoc = lp; sCe = cp; sNp = (float)np;
    }
  }
  __syncthreads();

  const float* row = confneg + (size_t)b * P;
  int K = sK;
  unsigned pfx = 0;
  int Krem = K;
#pragma unroll
  for (int pass = 3; pass >= 0; --pass) {
    int sh = pass * 8;
    for (int i = tid; i < 4 * 256; i += TPB2) u.s3.histw[i] = 0;
    __syncthreads();
    unsigned himask = (pass == 3) ? 0u : (0xFFFFFFFFu << (sh + 8));
    int* myh = &u.s3.histw[wid * 256];
    for (int k = 0; k < NR4; k++) {
      int i4 = (k << 8) + tid;
      if (i4 < P / 4) {
        // 4 independent sc1 loads issue back-to-back: one overlapped MALL
        // latency per group of 4 (element order matches the old float4 path)
        float v0 = LD_AGENT_F(row + 4 * i4 + 0);
        float v1 = LD_AGENT_F(row + 4 * i4 + 1);
        float v2 = LD_AGENT_F(row + 4 * i4 + 2);
        float v3 = LD_AGENT_F(row + 4 * i4 + 3);
        unsigned u0 = __float_as_uint(v0), u1 = __float_as_uint(v1);
        unsigned u2 = __float_as_uint(v2), u3 = __float_as_uint(v3);
        if ((u0 & himask) == pfx) atomicAdd(&myh[(u0 >> sh) & 255], 1);
        if ((u1 & himask) == pfx) atomicAdd(&myh[(u1 >> sh) & 255], 1);
        if ((u2 & himask) == pfx) atomicAdd(&myh[(u2 >> sh) & 255], 1);
        if ((u3 & himask) == pfx) atomicAdd(&myh[(u3 >> sh) & 255], 1);
      }
    }
    __syncthreads();
    {
      int c = u.s3.histw[tid] + u.s3.histw[256 + tid] +
              u.s3.histw[512 + tid] + u.s3.histw[768 + tid];
      u.s3.cnt[tid] = c;
    }
    __syncthreads();
    if (wid == 0) {
      int4 c4 = ((const int4*)u.s3.cnt)[lane];
      int s3v = c4.w;
      int s2 = c4.z + s3v;
      int s1 = c4.y + s2;
      int s0 = c4.x + s1;
      int suf = s0;
      for (int off = 1; off < 64; off <<= 1) {
        int t = __shfl_down(suf, off, 64);
        if (lane + off < 64) suf += t;
      }
      int above = suf - s0;
      int S0 = above + s0, S1 = above + s1, S2 = above + s2, S3 = above + s3v;
      int S4 = above;
      if (S3 >= Krem && S4 < Krem) { sdig = 4 * lane + 3; scum = S4; }
      else if (S2 >= Krem && S3 < Krem) { sdig = 4 * lane + 2; scum = S3; }
      else if (S1 >= Krem && S2 < Krem) { sdig = 4 * lane + 1; scum = S2; }
      else if (S0 >= Krem && S1 < Krem) { sdig = 4 * lane + 0; scum = S1; }
    }
    __syncthreads();
    pfx |= ((unsigned)sdig) << sh;
    Krem -= scum;
  }
  float tau = __uint_as_float(pfx);

  float sum = 0.0f;
  int cgt = 0;
  for (int k = 0; k < NR4; k++) {
    int i4 = (k << 8) + tid;
    if (i4 < P / 4) {
      float v0 = LD_AGENT_F(row + 4 * i4 + 0);
      float v1 = LD_AGENT_F(row + 4 * i4 + 1);
      float v2 = LD_AGENT_F(row + 4 * i4 + 2);
      float v3 = LD_AGENT_F(row + 4 * i4 + 3);
      if (v0 > tau) { sum += v0; cgt++; }
      if (v1 > tau) { sum += v1; cgt++; }
      if (v2 > tau) { sum += v2; cgt++; }
      if (v3 > tau) { sum += v3; cgt++; }
    }
  }
  for (int off = 32; off >= 1; off >>= 1) {
    sum += __shfl_down(sum, off, 64);
    cgt += __shfl_down(cgt, off, 64);
  }
  if (lane == 0) { u.s3.rsum[wid] = sum; u.s3.rcnt[wid] = cgt; }
  __syncthreads();
  if (tid == 0) {
    float stot = u.s3.rsum[0] + u.s3.rsum[1] + u.s3.rsum[2] + u.s3.rsum[3];
    int ctot = u.s3.rcnt[0] + u.s3.rcnt[1] + u.s3.rcnt[2] + u.s3.rcnt[3];
    float hard = stot + (float)(K - ctot) * tau;
    ST_AGENT(&imgres[b * 4 + 0], sLoc);
    ST_AGENT(&imgres[b * 4 + 1], sCe);
    ST_AGENT(&imgres[b * 4 + 2], hard);
    ST_AGENT(&imgres[b * 4 + 3], sNp);
    asm volatile("s_waitcnt vmcnt(0)" ::: "memory");  // imgres at L3
    int prev = __hip_atomic_fetch_add(done, 1, __ATOMIC_RELAXED,
                                      __HIP_MEMORY_SCOPE_AGENT);
    sLastImg = (prev == B - 1) ? 1 : 0;
  }
  __syncthreads();
  if (sLastImg) {
    // reads below are sc1 MALL-direct loads — no fence needed
    float l = 0.0f, c = 0.0f, h = 0.0f, n = 0.0f;
    if (tid < B) {
      l = LD_AGENT_F(&imgres[tid * 4 + 0]);
      c = LD_AGENT_F(&imgres[tid * 4 + 1]);
      h = LD_AGENT_F(&imgres[tid * 4 + 2]);
      n = LD_AGENT_F(&imgres[tid * 4 + 3]);
    }
    for (int off = 32; off >= 1; off >>= 1) {
      l += __shfl_down(l, off, 64);
      c += __shfl_down(c, off, 64);
      h += __shfl_down(h, off, 64);
      n += __shfl_down(n, off, 64);
    }
    if (lane == 0) { u.s3.rl[wid] = l; u.s3.rc[wid] = c; u.s3.rh[wid] = h; u.s3.rn[wid] = n; }
    __syncthreads();
    if (tid == 0) {
      float L = 0, Cc = 0, H = 0, N = 0;
#pragma unroll
      for (int w = 0; w < 4; w++) {
        L += u.s3.rl[w]; Cc += u.s3.rc[w]; H += u.s3.rh[w]; N += u.s3.rn[w];
      }
      float loc = ALPHA * L / (N * 4.0f);
      float conf = (H + Cc) / N;
      out[0] = conf + loc;
      out[1] = loc;
      out[2] = conf;
    }
  }
}

extern "C" void kernel_launch(void* const* d_in, const int* in_sizes, int n_in,
                              void* d_out, int out_size, void* d_ws, size_t ws_size,
                              hipStream_t stream) {
  (void)in_sizes; (void)n_in; (void)out_size; (void)ws_size;
  const float* pred_loc = (const float*)d_in[0];
  const float* pred_cls = (const float*)d_in[1];
  const float* b_boxes = (const float*)d_in[2];
  const int* b_labels = (const int*)d_in[3];
  const float* priors = (const float*)d_in[4];
  float* out = (float*)d_out;

  int* done = (int*)d_ws;
  int* imgcnt = (int*)d_ws + 8;
  float* ploc = (float*)d_ws + 8 + B;
  float* pce = ploc + B * NB2;
  int* pnp = (int*)(pce + B * NB2);
  float* imgres = (float*)(pnp + B * NB2);
  float* pI = imgres + B * 4;
  float* pU = pI + B * M * CH;
  int* pidx = (int*)(pU + B * M * CH);
  float* confneg = (float*)(pidx + B * M * CH);  // 16B-aligned

  k1_partial<<<B * CH, 256, 0, stream>>>(b_boxes, priors, pI, pU, pidx, done, imgcnt);
  dim3 g2(NB2, B);
  k23_fused<<<g2, TPB2, 0, stream>>>(pred_loc, pred_cls, b_boxes, b_labels,
                                     priors, pI, pU, pidx, ploc, pce, pnp,
                                     confneg, imgcnt, imgres, done, out);
}

// Round 7
// 246.906 us; speedup vs baseline: 1.1498x; 1.1498x over previous
//
#include <hip/hip_runtime.h>
#include <math.h>

#define B 128
#define M 32
#define P 8732
#define C 21
#define ALPHA 10.0f
#define NB2 35           // old per-image partial count (kept for exact sum order)
#define CH 8             // k1 prior chunks
#define CS 1092          // ceil(P / CH)

// ---------------- k1a: per-chunk best prior per object (partials) -----------
__global__ __launch_bounds__(256) void k1_partial(
    const float* __restrict__ b_boxes, const float* __restrict__ priors,
    float* __restrict__ pI, float* __restrict__ pU, int* __restrict__ pidx,
    int* __restrict__ done) {
  if (blockIdx.x == 0 && threadIdx.x == 0) *done = 0;
  int b = blockIdx.x >> 3;
  int ch = blockIdx.x & 7;
  int wid = threadIdx.x >> 6;
  int lane = threadIdx.x & 63;
  int obase = wid * 8;

  float ox1[8], oy1[8], ox2[8], oy2[8], oarea[8], bI[8], bU[8];
  int bidx[8];
#pragma unroll
  for (int k = 0; k < 8; k++) {
    float4 bx = ((const float4*)b_boxes)[(size_t)b * M + obase + k];
    ox1[k] = bx.x; oy1[k] = bx.y; ox2[k] = bx.z; oy2[k] = bx.w;
    oarea[k] = (bx.z - bx.x) * (bx.w - bx.y);
    bI[k] = -1.0f; bU[k] = 1.0f; bidx[k] = P;
  }

  int pend = (ch + 1) * CS;
  if (pend > P) pend = P;
#pragma unroll 2
  for (int p = ch * CS + lane; p < pend; p += 64) {
    float4 pr = ((const float4*)priors)[p];
    float pw2 = pr.z * 0.5f, ph2 = pr.w * 0.5f;
    float px1 = pr.x - pw2, py1 = pr.y - ph2;
    float px2 = pr.x + pw2, py2 = pr.y + ph2;
    float areaP = pr.z * pr.w;
#pragma unroll
    for (int k = 0; k < 8; k++) {
      float iw = fminf(ox2[k], px2) - fmaxf(ox1[k], px1);
      float ih = fminf(oy2[k], py2) - fmaxf(oy1[k], py1);
      iw = fmaxf(iw, 0.0f);
      ih = fmaxf(ih, 0.0f);
      float inter = iw * ih;
      float uni = oarea[k] + areaP - inter;
      if (inter * bU[k] > bI[k] * uni) { bI[k] = inter; bU[k] = uni; bidx[k] = p; }
    }
  }
  for (int off = 32; off >= 1; off >>= 1) {
#pragma unroll
    for (int k = 0; k < 8; k++) {
      float oI = __shfl_xor(bI[k], off, 64);
      float oU = __shfl_xor(bU[k], off, 64);
      int oi = __shfl_xor(bidx[k], off, 64);
      float l = oI * bU[k], r = bI[k] * oU;
      if (l > r || (l == r && oi < bidx[k])) { bI[k] = oI; bU[k] = oU; bidx[k] = oi; }
    }
  }
  if (lane == 0) {
#pragma unroll
    for (int k = 0; k < 8; k++) {
      int idx = ((size_t)b * M + obase + k) * CH + ch;
      pI[idx] = bI[k]; pU[idx] = bU[k]; pidx[idx] = bidx[k];
    }
  }
}

// ---------------- k23: ONE BLOCK PER IMAGE — match+CE into LDS, then radix --
// No cross-block handoff for confneg (it lives in LDS). Summation order is
// bitwise-identical to the old k2->k3 chain: per-64-prior-tile shfl trees,
// accumulated in old-block (x) order into 35 partials, then old wave-0 tree.
// Finalize is verbatim old k3 (threadfence + done counter): proven at the
// 214us baseline with 128 blocks.
__global__ __launch_bounds__(1024) void k23_img(
    const float* __restrict__ pred_loc, const float* __restrict__ pred_cls,
    const float* __restrict__ b_boxes, const int* __restrict__ b_labels,
    const float* __restrict__ priors,
    const float* __restrict__ pI, const float* __restrict__ pU,
    const int* __restrict__ pidx,
    float* __restrict__ imgres, int* __restrict__ done,
    float* __restrict__ out) {
  int b = blockIdx.x;
  int tid = threadIdx.x;
  int wid = tid >> 6;
  int lane = tid & 63;

  __shared__ __align__(16) float s[P];       // confneg row (never leaves LDS)
  __shared__ __align__(16) float4 sbox[M];
  __shared__ float sarea[M];
  __shared__ int slab[M], sobj[M];
  __shared__ float pl[NB2], pc[NB2];
  __shared__ int pn[NB2];
  __shared__ int histw[16 * 256];
  __shared__ __align__(16) int cnt[256];
  __shared__ int sdig, scum, sK, sLast;
  __shared__ float sLoc, sCe, sNp;
  __shared__ float rsum[16], rl[16], rc[16], rh[16], rn[16];
  __shared__ int rcnt[16];

  if (tid < M) {
    int m = tid;
    float4 bx = ((const float4*)b_boxes)[b * M + m];
    sbox[m] = bx;
    sarea[m] = (bx.z - bx.x) * (bx.w - bx.y);
    slab[m] = b_labels[b * M + m];
    // fused k1_reduce: fold 8 chunk partials for object m of image b
    int o = b * M + m;
    float cI = pI[o * CH], cU = pU[o * CH];
    int ci = pidx[o * CH];
#pragma unroll
    for (int ch = 1; ch < CH; ch++) {
      float nI = pI[o * CH + ch], nU = pU[o * CH + ch];
      int ni = pidx[o * CH + ch];
      if (nI * cU > cI * nU) { cI = nI; cU = nU; ci = ni; }
    }
    sobj[m] = ci;
  }
  __syncthreads();

  // ---------- phase A: wave W owns old-blocks x = W, W+16, W+32 (< 35) ------
  for (int x = wid; x < NB2; x += 16) {
    float accl = 0.0f, accc = 0.0f;
    int accn = 0;
    for (int w4 = 0; w4 < 4; w4++) {   // old waves 0..3 of old block x, in order
      int p = x * 256 + w4 * 64 + lane;
      float locpart = 0.0f, cepospart = 0.0f;
      int npos = 0;
      if (p < P) {
        float4 pr = ((const float4*)priors)[p];
        float pw2 = pr.z * 0.5f, ph2 = pr.w * 0.5f;
        float px1 = pr.x - pw2, py1 = pr.y - ph2;
        float px2 = pr.x + pw2, py2 = pr.y + ph2;
        float areaP = pr.z * pr.w;
        float bI = -1.0f, bU = 1.0f;
        int bm = 0;
        int fm = 0x7fffffff;   // first (min) object forcing this prior
        for (int m = 0; m < M; m++) {
          float4 bx = sbox[m];  // ds_read_b128 broadcast per object
          float iw = fminf(bx.z, px2) - fmaxf(bx.x, px1);
          float ih = fminf(bx.w, py2) - fmaxf(bx.y, py1);
          iw = fmaxf(iw, 0.0f);
          ih = fmaxf(ih, 0.0f);
          float inter = iw * ih;
          float uni = sarea[m] + areaP - inter;
          if (inter * bU > bI * uni) { bI = inter; bU = uni; bm = m; }
          if (fm == 0x7fffffff && sobj[m] == p) fm = m;
        }
        // forced best-prior override (first-max semantics preserved)
        if (fm != 0x7fffffff) {
          if (!((bI == bU) && (bm < fm))) { bI = 1.0f; bU = 1.0f; bm = fm; }
        }
        bool pos = (2.0f * bI >= bU);  // iou >= 0.5, division-free
        int wAny = __any((int)pos);

        if (wAny) {  // wave-uniform positive path
          float4 plv = ((const float4*)pred_loc)[(size_t)b * P + p];
          float4 bx = sbox[bm];
          float cx = (bx.x + bx.z) * 0.5f, cy = (bx.y + bx.w) * 0.5f;
          float w = bx.z - bx.x, h = bx.w - bx.y;
          float rz = __builtin_amdgcn_rcpf(pr.z);
          float rw = __builtin_amdgcn_rcpf(pr.w);
          float g0 = (cx - pr.x) * 10.0f * rz;
          float g1 = (cy - pr.y) * 10.0f * rw;
          float g2 = __logf(w * rz) * 5.0f;
          float g3 = __logf(h * rw) * 5.0f;
          if (pos) {
            locpart = fabsf(plv.x - g0) + fabsf(plv.y - g1) +
                      fabsf(plv.z - g2) + fabsf(plv.w - g3);
            npos = 1;
          }
        }

        // CE directly from global (same values the old LDS tile held)
        const float* uu = pred_cls + ((size_t)b * P + p) * C;
        int cls = pos ? slab[bm] : 0;
        float se = 0.0f, vc = 0.0f;
#pragma unroll
        for (int c = 0; c < C; c++) {
          float xv = uu[c];
          se += __expf(xv);
          if (c == cls) vc = xv;
        }
        float ce = __logf(se) - vc;
        s[p] = pos ? 0.0f : ce;      // confneg stays in LDS
        cepospart = pos ? ce : 0.0f;
      }
      // wave reduce (same tree as old k2)
      for (int off = 32; off >= 1; off >>= 1) {
        locpart += __shfl_down(locpart, off, 64);
        cepospart += __shfl_down(cepospart, off, 64);
        npos += __shfl_down(npos, off, 64);
      }
      if (lane == 0) { accl += locpart; accc += cepospart; accn += npos; }
    }
    if (lane == 0) { pl[x] = accl; pc[x] = accc; pn[x] = accn; }
  }
  __syncthreads();

  // ---------- per-image partial reduce (verbatim old k3 wave-0 tree) --------
  if (wid == 0) {
    float lp = 0.0f, cp = 0.0f;
    int np = 0;
    if (lane < NB2) { lp = pl[lane]; cp = pc[lane]; np = pn[lane]; }
    for (int off = 32; off >= 1; off >>= 1) {
      lp += __shfl_down(lp, off, 64);
      cp += __shfl_down(cp, off, 64);
      np += __shfl_down(np, off, 64);
    }
    if (lane == 0) {
      int K = np * 3;
      if (K > P) K = P;
      sK = K; sLoc = lp; sCe = cp; sNp = (float)np;
    }
  }
  __syncthreads();

  // ---------- radix top-K over LDS s[] (verbatim old k3) --------------------
  int K = sK;
  unsigned pfx = 0;
  int Krem = K;
#pragma unroll
  for (int pass = 3; pass >= 0; --pass) {
    int sh = pass * 8;
    for (int i = tid; i < 16 * 256; i += 1024) histw[i] = 0;
    __syncthreads();
    unsigned himask = (pass == 3) ? 0u : (0xFFFFFFFFu << (sh + 8));
    int* myh = &histw[wid * 256];
    for (int i = tid; i < P; i += 1024) {
      unsigned ub = __float_as_uint(s[i]);
      if ((ub & himask) == pfx) atomicAdd(&myh[(ub >> sh) & 255], 1);
    }
    __syncthreads();
    if (tid < 256) {
      int c = 0;
#pragma unroll
      for (int w = 0; w < 16; w++) c += histw[w * 256 + tid];
      cnt[tid] = c;
    }
    __syncthreads();
    if (wid == 0) {
      int4 c4 = ((const int4*)cnt)[lane];
      int s3 = c4.w;
      int s2 = c4.z + s3;
      int s1 = c4.y + s2;
      int s0 = c4.x + s1;
      int suf = s0;
      for (int off = 1; off < 64; off <<= 1) {
        int t = __shfl_down(suf, off, 64);
        if (lane + off < 64) suf += t;
      }
      int above = suf - s0;
      int S0 = above + s0, S1 = above + s1, S2 = above + s2, S3 = above + s3;
      int S4 = above;
      if (S3 >= Krem && S4 < Krem) { sdig = 4 * lane + 3; scum = S4; }
      else if (S2 >= Krem && S3 < Krem) { sdig = 4 * lane + 2; scum = S3; }
      else if (S1 >= Krem && S2 < Krem) { sdig = 4 * lane + 1; scum = S2; }
      else if (S0 >= Krem && S1 < Krem) { sdig = 4 * lane + 0; scum = S1; }
    }
    __syncthreads();
    pfx |= ((unsigned)sdig) << sh;
    Krem -= scum;
  }
  float tau = __uint_as_float(pfx);

  float sum = 0.0f;
  int cgt = 0;
  for (int i = tid; i < P; i += 1024) {
    float v = s[i];
    if (v > tau) { sum += v; cgt++; }
  }
  for (int off = 32; off >= 1; off >>= 1) {
    sum += __shfl_down(sum, off, 64);
    cgt += __shfl_down(cgt, off, 64);
  }
  if (lane == 0) { rsum[wid] = sum; rcnt[wid] = cgt; }
  __syncthreads();
  if (tid == 0) {
    float stot = 0.0f;
    int ctot = 0;
#pragma unroll
    for (int w = 0; w < 16; w++) { stot += rsum[w]; ctot += rcnt[w]; }
    float hard = stot + (float)(K - ctot) * tau;
    imgres[b * 4 + 0] = sLoc;
    imgres[b * 4 + 1] = sCe;
    imgres[b * 4 + 2] = hard;
    imgres[b * 4 + 3] = sNp;
    __threadfence();
    int prev = atomicAdd(done, 1);
    sLast = (prev == B - 1) ? 1 : 0;
  }
  __syncthreads();
  if (sLast) {
    __threadfence();
    float l = 0.0f, c = 0.0f, h = 0.0f, n = 0.0f;
    if (tid < B) {
      l = atomicAdd(&imgres[tid * 4 + 0], 0.0f);
      c = atomicAdd(&imgres[tid * 4 + 1], 0.0f);
      h = atomicAdd(&imgres[tid * 4 + 2], 0.0f);
      n = atomicAdd(&imgres[tid * 4 + 3], 0.0f);
    }
    for (int off = 32; off >= 1; off >>= 1) {
      l += __shfl_down(l, off, 64);
      c += __shfl_down(c, off, 64);
      h += __shfl_down(h, off, 64);
      n += __shfl_down(n, off, 64);
    }
    if (lane == 0) { rl[wid] = l; rc[wid] = c; rh[wid] = h; rn[wid] = n; }
    __syncthreads();
    if (tid == 0) {
      float L = 0, Cc = 0, H = 0, N = 0;
#pragma unroll
      for (int w = 0; w < 16; w++) { L += rl[w]; Cc += rc[w]; H += rh[w]; N += rn[w]; }
      float loc = ALPHA * L / (N * 4.0f);
      float conf = (H + Cc) / N;
      out[0] = conf + loc;
      out[1] = loc;
      out[2] = conf;
    }
  }
}

extern "C" void kernel_launch(void* const* d_in, const int* in_sizes, int n_in,
                              void* d_out, int out_size, void* d_ws, size_t ws_size,
                              hipStream_t stream) {
  (void)in_sizes; (void)n_in; (void)out_size; (void)ws_size;
  const float* pred_loc = (const float*)d_in[0];
  const float* pred_cls = (const float*)d_in[1];
  const float* b_boxes = (const float*)d_in[2];
  const int* b_labels = (const int*)d_in[3];
  const float* priors = (const float*)d_in[4];
  float* out = (float*)d_out;

  int* done = (int*)d_ws;
  float* imgres = (float*)d_ws + 8;
  float* pI = imgres + B * 4;
  float* pU = pI + B * M * CH;
  int* pidx = (int*)(pU + B * M * CH);

  k1_partial<<<B * CH, 256, 0, stream>>>(b_boxes, priors, pI, pU, pidx, done);
  k23_img<<<B, 1024, 0, stream>>>(pred_loc, pred_cls, b_boxes, b_labels,
                                  priors, pI, pU, pidx, imgres, done, out);
}

// Round 8
// 228.340 us; speedup vs baseline: 1.2433x; 1.0813x over previous
//
#include <hip/hip_runtime.h>
#include <math.h>

#define B 128
#define M 32
#define P 8732
#define C 21
#define ALPHA 10.0f
#define NB2 35           // old per-image partial count (kept for exact sum order)
#define NSUB 140         // 35*4 sub-tiles of 64 priors
#define CH 8             // k1 prior chunks
#define CS 1092          // ceil(P / CH)

typedef float fx4 __attribute__((ext_vector_type(4)));
typedef fx4 fx4u __attribute__((aligned(4)));   // under-aligned vector load

#define CE1(val, idx) { float xv_ = (val); se += __expf(xv_); if (cls == (idx)) vc = xv_; }

// ---------------- k1a: per-chunk best prior per object (partials) -----------
__global__ __launch_bounds__(256) void k1_partial(
    const float* __restrict__ b_boxes, const float* __restrict__ priors,
    float* __restrict__ pI, float* __restrict__ pU, int* __restrict__ pidx,
    int* __restrict__ done) {
  if (blockIdx.x == 0 && threadIdx.x == 0) *done = 0;
  int b = blockIdx.x >> 3;
  int ch = blockIdx.x & 7;
  int wid = threadIdx.x >> 6;
  int lane = threadIdx.x & 63;
  int obase = wid * 8;

  float ox1[8], oy1[8], ox2[8], oy2[8], oarea[8], bI[8], bU[8];
  int bidx[8];
#pragma unroll
  for (int k = 0; k < 8; k++) {
    float4 bx = ((const float4*)b_boxes)[(size_t)b * M + obase + k];
    ox1[k] = bx.x; oy1[k] = bx.y; ox2[k] = bx.z; oy2[k] = bx.w;
    oarea[k] = (bx.z - bx.x) * (bx.w - bx.y);
    bI[k] = -1.0f; bU[k] = 1.0f; bidx[k] = P;
  }

  int pend = (ch + 1) * CS;
  if (pend > P) pend = P;
#pragma unroll 2
  for (int p = ch * CS + lane; p < pend; p += 64) {
    float4 pr = ((const float4*)priors)[p];
    float pw2 = pr.z * 0.5f, ph2 = pr.w * 0.5f;
    float px1 = pr.x - pw2, py1 = pr.y - ph2;
    float px2 = pr.x + pw2, py2 = pr.y + ph2;
    float areaP = pr.z * pr.w;
#pragma unroll
    for (int k = 0; k < 8; k++) {
      float iw = fminf(ox2[k], px2) - fmaxf(ox1[k], px1);
      float ih = fminf(oy2[k], py2) - fmaxf(oy1[k], py1);
      iw = fmaxf(iw, 0.0f);
      ih = fmaxf(ih, 0.0f);
      float inter = iw * ih;
      float uni = oarea[k] + areaP - inter;
      if (inter * bU[k] > bI[k] * uni) { bI[k] = inter; bU[k] = uni; bidx[k] = p; }
    }
  }
  for (int off = 32; off >= 1; off >>= 1) {
#pragma unroll
    for (int k = 0; k < 8; k++) {
      float oI = __shfl_xor(bI[k], off, 64);
      float oU = __shfl_xor(bU[k], off, 64);
      int oi = __shfl_xor(bidx[k], off, 64);
      float l = oI * bU[k], r = bI[k] * oU;
      if (l > r || (l == r && oi < bidx[k])) { bI[k] = oI; bU[k] = oU; bidx[k] = oi; }
    }
  }
  if (lane == 0) {
#pragma unroll
    for (int k = 0; k < 8; k++) {
      int idx = ((size_t)b * M + obase + k) * CH + ch;
      pI[idx] = bI[k]; pU[idx] = bU[k]; pidx[idx] = bidx[k];
    }
  }
}

// ---------------- phase A worker: KN register-cached tiles per wave ---------
// Loop interchange: object loop OUTSIDE prior loop -> 32 ds_read_b128 per wave
// per group (was 64 LDS reads PER PRIOR = LDS-pipe-bound, the 66us of R7).
// All FP orders bitwise-match the old per-prior chain.
template <int KN>
__device__ __forceinline__ void phaseA_group(
    int b, int wid, int lane, int koff, int ntw,
    const float* __restrict__ pred_loc, const float* __restrict__ pred_cls,
    const float* __restrict__ priors,
    const float4* sbox, const int* slab, const int* sobj,
    float* s, float* psl, float* psc, int* psn) {
  float x1[KN], y1[KN], x2[KN], y2[KN], ap[KN];
  float bIr[KN], bUr[KN];
  int bmr[KN], fmr[KN];
#pragma unroll
  for (int j = 0; j < KN; j++) {
    int k = koff + j;
    int p = ((wid + (k << 4)) << 6) + lane;
    x1[j] = 0.0f; y1[j] = 0.0f; x2[j] = 0.0f; y2[j] = 0.0f; ap[j] = 0.0f;
    bIr[j] = -1.0f; bUr[j] = 1.0f; bmr[j] = 0; fmr[j] = 0x7fffffff;
    if (k < ntw && p < P) {
      float4 pr = ((const float4*)priors)[p];
      float pw2 = pr.z * 0.5f, ph2 = pr.w * 0.5f;
      x1[j] = pr.x - pw2; y1[j] = pr.y - ph2;
      x2[j] = pr.x + pw2; y2[j] = pr.y + ph2;
      ap[j] = pr.z * pr.w;
    }
  }
  for (int m = 0; m < M; m++) {
    float4 bx = sbox[m];                       // ONE broadcast read per object
    float areaB = (bx.z - bx.x) * (bx.w - bx.y);  // == old sarea[m] bitwise
    int objm = sobj[m];
#pragma unroll
    for (int j = 0; j < KN; j++) {
      float iw = fminf(bx.z, x2[j]) - fmaxf(bx.x, x1[j]);
      float ih = fminf(bx.w, y2[j]) - fmaxf(bx.y, y1[j]);
      iw = fmaxf(iw, 0.0f);
      ih = fmaxf(ih, 0.0f);
      float inter = iw * ih;
      float uni = areaB + ap[j] - inter;
      if (inter * bUr[j] > bIr[j] * uni) { bIr[j] = inter; bUr[j] = uni; bmr[j] = m; }
      int p = ((wid + ((koff + j) << 4)) << 6) + lane;
      if (fmr[j] == 0x7fffffff && objm == p) fmr[j] = m;
    }
  }
#pragma unroll
  for (int j = 0; j < KN; j++) {
    int k = koff + j;
    if (k < ntw) {                     // wave-uniform guard
      int t = wid + (k << 4);
      int p = (t << 6) + lane;
      float locpart = 0.0f, cepospart = 0.0f;
      int npos = 0;
      if (p < P) {
        float bIv = bIr[j], bUv = bUr[j];
        int bmv = bmr[j], fmv = fmr[j];
        // forced best-prior override (first-max semantics preserved)
        if (fmv != 0x7fffffff) {
          if (!((bIv == bUv) && (bmv < fmv))) { bIv = 1.0f; bUv = 1.0f; bmv = fmv; }
        }
        bool pos = (2.0f * bIv >= bUv);  // iou >= 0.5, division-free
        int wAny = __any((int)pos);
        if (wAny) {                      // wave-uniform positive path
          float4 pr = ((const float4*)priors)[p];   // reload (L2-hot)
          float4 plv = ((const float4*)pred_loc)[(size_t)b * P + p];
          float4 bx = sbox[bmv];
          float cx = (bx.x + bx.z) * 0.5f, cy = (bx.y + bx.w) * 0.5f;
          float w = bx.z - bx.x, h = bx.w - bx.y;
          float rz = __builtin_amdgcn_rcpf(pr.z);
          float rw = __builtin_amdgcn_rcpf(pr.w);
          float g0 = (cx - pr.x) * 10.0f * rz;
          float g1 = (cy - pr.y) * 10.0f * rw;
          float g2 = __logf(w * rz) * 5.0f;
          float g3 = __logf(h * rw) * 5.0f;
          if (pos) {
            locpart = fabsf(plv.x - g0) + fabsf(plv.y - g1) +
                      fabsf(plv.z - g2) + fabsf(plv.w - g3);
            npos = 1;
          }
        }
        // CE: 5 x dwordx4 (align-4) + 1 scalar instead of 21 scalar loads
        int cls = pos ? slab[bmv] : 0;
        const float* uu = pred_cls + ((size_t)b * P + p) * C;
        const fx4u* u4 = (const fx4u*)uu;
        fx4 a0 = u4[0], a1 = u4[1], a2 = u4[2], a3 = u4[3], a4 = u4[4];
        float v20 = uu[20];
        float se = 0.0f, vc = 0.0f;
        CE1(a0.x, 0)  CE1(a0.y, 1)  CE1(a0.z, 2)  CE1(a0.w, 3)
        CE1(a1.x, 4)  CE1(a1.y, 5)  CE1(a1.z, 6)  CE1(a1.w, 7)
        CE1(a2.x, 8)  CE1(a2.y, 9)  CE1(a2.z, 10) CE1(a2.w, 11)
        CE1(a3.x, 12) CE1(a3.y, 13) CE1(a3.z, 14) CE1(a3.w, 15)
        CE1(a4.x, 16) CE1(a4.y, 17) CE1(a4.z, 18) CE1(a4.w, 19)
        CE1(v20, 20)
        float ce = __logf(se) - vc;
        s[p] = pos ? 0.0f : ce;      // confneg stays in LDS
        cepospart = pos ? ce : 0.0f;
      }
      // wave reduce (same tree as old k2; all 64 lanes participate)
      for (int off = 32; off >= 1; off >>= 1) {
        locpart += __shfl_down(locpart, off, 64);
        cepospart += __shfl_down(cepospart, off, 64);
        npos += __shfl_down(npos, off, 64);
      }
      if (lane == 0) { psl[t] = locpart; psc[t] = cepospart; psn[t] = npos; }
    }
  }
}

// ---------------- k23: ONE BLOCK PER IMAGE — match+CE into LDS, then radix --
__global__ __launch_bounds__(1024) void k23_img(
    const float* __restrict__ pred_loc, const float* __restrict__ pred_cls,
    const float* __restrict__ b_boxes, const int* __restrict__ b_labels,
    const float* __restrict__ priors,
    const float* __restrict__ pI, const float* __restrict__ pU,
    const int* __restrict__ pidx,
    float* __restrict__ imgres, int* __restrict__ done,
    float* __restrict__ out) {
  int b = blockIdx.x;
  int tid = threadIdx.x;
  int wid = tid >> 6;
  int lane = tid & 63;

  __shared__ __align__(16) float s[P];       // confneg row (never leaves LDS)
  __shared__ __align__(16) float4 sbox[M];
  __shared__ int slab[M], sobj[M];
  __shared__ float psl[NSUB], psc[NSUB];     // per-64-prior-subtile partials
  __shared__ int psn[NSUB];
  __shared__ int histw[16 * 256];
  __shared__ __align__(16) int cnt[256];
  __shared__ int sdig, scum, sK, sLast;
  __shared__ float sLoc, sCe, sNp;
  __shared__ float rsum[16], rl[16], rc[16], rh[16], rn[16];
  __shared__ int rcnt[16];

  if (tid < M) {
    int m = tid;
    float4 bx = ((const float4*)b_boxes)[b * M + m];
    sbox[m] = bx;
    slab[m] = b_labels[b * M + m];
    // fused k1_reduce: fold 8 chunk partials for object m of image b
    int o = b * M + m;
    float cI = pI[o * CH], cU = pU[o * CH];
    int ci = pidx[o * CH];
#pragma unroll
    for (int ch = 1; ch < CH; ch++) {
      float nI = pI[o * CH + ch], nU = pU[o * CH + ch];
      int ni = pidx[o * CH + ch];
      if (nI * cU > cI * nU) { cI = nI; cU = nU; ci = ni; }
    }
    sobj[m] = ci;
  }
  __syncthreads();

  // ---------- phase A: 140 sub-tiles over 16 waves, 5+4 register groups -----
  int ntw = (wid < 12) ? 9 : 8;    // sub-tiles per wave (t = wid + k*16 < 140)
  phaseA_group<5>(b, wid, lane, 0, ntw, pred_loc, pred_cls, priors,
                  sbox, slab, sobj, s, psl, psc, psn);
  phaseA_group<4>(b, wid, lane, 5, ntw, pred_loc, pred_cls, priors,
                  sbox, slab, sobj, s, psl, psc, psn);
  __syncthreads();

  // ---------- per-image partial reduce (old order: 4-subtile chain + tree) --
  if (wid == 0) {
    float lp = 0.0f, cp = 0.0f;
    int np = 0;
    if (lane < NB2) {
      int t4 = lane * 4;
      lp = ((psl[t4] + psl[t4 + 1]) + psl[t4 + 2]) + psl[t4 + 3];
      cp = ((psc[t4] + psc[t4 + 1]) + psc[t4 + 2]) + psc[t4 + 3];
      np = psn[t4] + psn[t4 + 1] + psn[t4 + 2] + psn[t4 + 3];
    }
    for (int off = 32; off >= 1; off >>= 1) {
      lp += __shfl_down(lp, off, 64);
      cp += __shfl_down(cp, off, 64);
      np += __shfl_down(np, off, 64);
    }
    if (lane == 0) {
      int K = np * 3;
      if (K > P) K = P;
      sK = K; sLoc = lp; sCe = cp; sNp = (float)np;
    }
  }
  __syncthreads();

  // ---------- radix top-K over LDS s[] (unchanged) --------------------------
  int K = sK;
  unsigned pfx = 0;
  int Krem = K;
#pragma unroll
  for (int pass = 3; pass >= 0; --pass) {
    int sh = pass * 8;
    for (int i = tid; i < 16 * 256; i += 1024) histw[i] = 0;
    __syncthreads();
    unsigned himask = (pass == 3) ? 0u : (0xFFFFFFFFu << (sh + 8));
    int* myh = &histw[wid * 256];
    for (int i = tid; i < P; i += 1024) {
      unsigned ub = __float_as_uint(s[i]);
      if ((ub & himask) == pfx) atomicAdd(&myh[(ub >> sh) & 255], 1);
    }
    __syncthreads();
    if (tid < 256) {
      int c = 0;
#pragma unroll
      for (int w = 0; w < 16; w++) c += histw[w * 256 + tid];
      cnt[tid] = c;
    }
    __syncthreads();
    if (wid == 0) {
      int4 c4 = ((const int4*)cnt)[lane];
      int s3 = c4.w;
      int s2 = c4.z + s3;
      int s1 = c4.y + s2;
      int s0 = c4.x + s1;
      int suf = s0;
      for (int off = 1; off < 64; off <<= 1) {
        int t = __shfl_down(suf, off, 64);
        if (lane + off < 64) suf += t;
      }
      int above = suf - s0;
      int S0 = above + s0, S1 = above + s1, S2 = above + s2, S3 = above + s3;
      int S4 = above;
      if (S3 >= Krem && S4 < Krem) { sdig = 4 * lane + 3; scum = S4; }
      else if (S2 >= Krem && S3 < Krem) { sdig = 4 * lane + 2; scum = S3; }
      else if (S1 >= Krem && S2 < Krem) { sdig = 4 * lane + 1; scum = S2; }
      else if (S0 >= Krem && S1 < Krem) { sdig = 4 * lane + 0; scum = S1; }
    }
    __syncthreads();
    pfx |= ((unsigned)sdig) << sh;
    Krem -= scum;
  }
  float tau = __uint_as_float(pfx);

  float sum = 0.0f;
  int cgt = 0;
  for (int i = tid; i < P; i += 1024) {
    float v = s[i];
    if (v > tau) { sum += v; cgt++; }
  }
  for (int off = 32; off >= 1; off >>= 1) {
    sum += __shfl_down(sum, off, 64);
    cgt += __shfl_down(cgt, off, 64);
  }
  if (lane == 0) { rsum[wid] = sum; rcnt[wid] = cgt; }
  __syncthreads();
  if (tid == 0) {
    float stot = 0.0f;
    int ctot = 0;
#pragma unroll
    for (int w = 0; w < 16; w++) { stot += rsum[w]; ctot += rcnt[w]; }
    float hard = stot + (float)(K - ctot) * tau;
    imgres[b * 4 + 0] = sLoc;
    imgres[b * 4 + 1] = sCe;
    imgres[b * 4 + 2] = hard;
    imgres[b * 4 + 3] = sNp;
    __threadfence();
    int prev = atomicAdd(done, 1);
    sLast = (prev == B - 1) ? 1 : 0;
  }
  __syncthreads();
  if (sLast) {
    __threadfence();
    float l = 0.0f, c = 0.0f, h = 0.0f, n = 0.0f;
    if (tid < B) {
      l = atomicAdd(&imgres[tid * 4 + 0], 0.0f);
      c = atomicAdd(&imgres[tid * 4 + 1], 0.0f);
      h = atomicAdd(&imgres[tid * 4 + 2], 0.0f);
      n = atomicAdd(&imgres[tid * 4 + 3], 0.0f);
    }
    for (int off = 32; off >= 1; off >>= 1) {
      l += __shfl_down(l, off, 64);
      c += __shfl_down(c, off, 64);
      h += __shfl_down(h, off, 64);
      n += __shfl_down(n, off, 64);
    }
    if (lane == 0) { rl[wid] = l; rc[wid] = c; rh[wid] = h; rn[wid] = n; }
    __syncthreads();
    if (tid == 0) {
      float L = 0, Cc = 0, H = 0, N = 0;
#pragma unroll
      for (int w = 0; w < 16; w++) { L += rl[w]; Cc += rc[w]; H += rh[w]; N += rn[w]; }
      float loc = ALPHA * L / (N * 4.0f);
      float conf = (H + Cc) / N;
      out[0] = conf + loc;
      out[1] = loc;
      out[2] = conf;
    }
  }
}

extern "C" void kernel_launch(void* const* d_in, const int* in_sizes, int n_in,
                              void* d_out, int out_size, void* d_ws, size_t ws_size,
                              hipStream_t stream) {
  (void)in_sizes; (void)n_in; (void)out_size; (void)ws_size;
  const float* pred_loc = (const float*)d_in[0];
  const float* pred_cls = (const float*)d_in[1];
  const float* b_boxes = (const float*)d_in[2];
  const int* b_labels = (const int*)d_in[3];
  const float* priors = (const float*)d_in[4];
  float* out = (float*)d_out;

  int* done = (int*)d_ws;
  float* imgres = (float*)d_ws + 8;
  float* pI = imgres + B * 4;
  float* pU = pI + B * M * CH;
  int* pidx = (int*)(pU + B * M * CH);

  k1_partial<<<B * CH, 256, 0, stream>>>(b_boxes, priors, pI, pU, pidx, done);
  k23_img<<<B, 1024, 0, stream>>>(pred_loc, pred_cls, b_boxes, b_labels,
                                  priors, pI, pU, pidx, imgres, done, out);
}